// Round 18
// baseline (828.315 us; speedup 1.0000x reference)
//
#include <hip/hip_runtime.h>
#include <math.h>

#define B 4
#define CG 256
#define CM 128
#define CA 128
#define H 128
#define W_ 128
#define HS 64
#define WS 64
#define L 4096
#define D1 1152
#define D2 2048
#define NPIX 65536
#define NT1 36
#define NT2 128

// slot layout (floats): [STP bf16 L*L][RA: Whi bf16 -> At bf16][RB: Z bf16]
#define STP_F 8388608UL
#define RA_F  4194304UL
#define SLOT_F (STP_F + RA_F + RA_F)   // 16,777,216 floats = 67.1 MB

typedef unsigned short u16;
typedef __attribute__((ext_vector_type(8))) short short8v;
typedef __attribute__((ext_vector_type(4))) unsigned short u16x4;
typedef __attribute__((ext_vector_type(4))) float f32x4;

__device__ __forceinline__ float bf2f(u16 x) {
    union { unsigned int u; float f; } v; v.u = ((unsigned int)x) << 16; return v.f;
}
__device__ __forceinline__ u16 f2bf(float x) {
    union { float f; unsigned int u; } v; v.f = x;
    unsigned int r = (v.u + 0x7FFFu + ((v.u >> 16) & 1u)) >> 16;
    return (u16)r;
}
__device__ __forceinline__ void gll16(const void* g, void* l) {
    __builtin_amdgcn_global_load_lds((const __attribute__((address_space(1))) void*)g,
                                     (__attribute__((address_space(3))) void*)l, 16, 0, 0);
}
__device__ __forceinline__ int refl(int i, int n) {
    return i < 0 ? -i : (i >= n ? 2 * n - 2 - i : i);
}
// swizzled LDS element offset for [128][32 u16] tiles (gemm1; 0-conflict per R5)
__device__ __forceinline__ int swz(int row, int fq) {
    return row * 32 + ((fq ^ ((row >> 1) & 3)) * 8);
}
// gemm2 [256][32 u16] tiles, 64B rows, (r>>1)&3 chunk-XOR (0-conflict per R9)
__device__ __forceinline__ short8v rdfrag32(const char* lds, int r, int fq) {
    return *(const short8v*)(lds + r * 64 + ((fq * 16) ^ (((r >> 1) & 3) << 4)));
}

// K0: f_ds = 1x1 conv at even pixels + fused ssq
__global__ __launch_bounds__(256) void k_conv_ds(const float* __restrict__ f,
                                                 const float* __restrict__ gw,
                                                 const float* __restrict__ gb,
                                                 float* __restrict__ fds,
                                                 float* __restrict__ ssq) {
    __shared__ float sf[CG * 64];
    __shared__ float part[4][64];
    int t = threadIdx.x;
    int hs = blockIdx.x, b = blockIdx.y;
    const float* fb = f + (size_t)b * CG * H * W_ + (2 * hs) * W_;
    for (int idx = t; idx < CG * 64; idx += 256) {
        int ci = idx >> 6, ws = idx & 63;
        sf[idx] = fb[(size_t)ci * H * W_ + 2 * ws];
    }
    __syncthreads();
    int ws = t & 63;
    int wave = __builtin_amdgcn_readfirstlane(t >> 6);
    const float* gwp = gw + (size_t)(wave * 32) * CG;
    float acc[32];
#pragma unroll
    for (int r = 0; r < 32; ++r) acc[r] = gb[wave * 32 + r];
    for (int ci = 0; ci < CG; ++ci) {
        float fv = sf[ci * 64 + ws];
#pragma unroll
        for (int r = 0; r < 32; ++r) acc[r] += gwp[r * CG + ci] * fv;
    }
    float sq = 0.f;
#pragma unroll
    for (int r = 0; r < 32; ++r) {
        int co = wave * 32 + r;
        fds[(((size_t)b * CM + co) * HS + hs) * WS + ws] = acc[r];
        sq += acc[r] * acc[r];
    }
    part[wave][ws] = sq;
    __syncthreads();
    if (t < 64)
        ssq[((size_t)b * HS + hs) * WS + t] =
            part[0][t] + part[1][t] + part[2][t] + part[3][t];
}

__global__ __launch_bounds__(256) void k_scale(const float* __restrict__ unk,
                                               float* __restrict__ suk,
                                               float* __restrict__ out2) {
    int b = blockIdx.x, t = threadIdx.x;
    __shared__ float red[256];
    float s = 0.f;
    for (int i = t; i < L; i += 256) {
        int hs = i >> 6, ws = i & 63;
        s += unk[(size_t)b * H * W_ + (2 * hs) * W_ + 2 * ws];
    }
    red[t] = s;
    __syncthreads();
    for (int o = 128; o > 0; o >>= 1) {
        if (t < o) red[t] += red[t + o];
        __syncthreads();
    }
    if (t == 0) {
        float u = red[0] / (float)L;
        float k = 1.0f - u;
        float su = sqrtf(u / k); su = fminf(fmaxf(su, 0.1f), 10.0f);
        float sk = sqrtf(k / u); sk = fminf(fmaxf(sk, 0.1f), 10.0f);
        suk[b * 2] = su; suk[b * 2 + 1] = sk;
        out2[b * 2] = su; out2[b * 2 + 1] = sk;
    }
}

__global__ __launch_bounds__(64) void k_gate(const float* __restrict__ unk,
                                             const float* __restrict__ ssq,
                                             const float* __restrict__ suk,
                                             float* __restrict__ g,
                                             float* __restrict__ dg) {
    int ws = threadIdx.x, hs = blockIdx.x, b = blockIdx.y;
    float sm = 0.f, sq = 0.f;
    for (int di = -1; di <= 1; ++di) {
        int rh = refl(hs + di, HS);
        for (int dj = -1; dj <= 1; ++dj) {
            int rw = refl(ws + dj, WS);
            sm += unk[(size_t)b * H * W_ + (2 * rh) * W_ + 2 * rw];
            sq += ssq[((size_t)b * HS + rh) * WS + rw];
        }
    }
    float mm   = (sm > 0.0f) ? 1.0f : 0.0f;
    float norm = sqrtf(sq);
    float gate = (mm > 0.0f) ? suk[2 * b] : suk[2 * b + 1];
    int q = hs * WS + ws;
    g[(size_t)b * L + q]  = gate / fmaxf(norm, 1e-4f);
    dg[(size_t)b * L + q] = -10000.0f * mm;
}

// K4: bf16 W (lanes over ws, broadcast reads — A/B proven form)
__global__ __launch_bounds__(256) void k_buildW(const float* __restrict__ fds,
                                                float* __restrict__ base, int b0) {
    int bz = blockIdx.z;
    int b  = b0 + bz;
    u16* Whi = (u16*)(base + (size_t)bz * SLOT_F + STP_F);
    int ws = threadIdx.x;
    int c  = blockIdx.y * 4 + threadIdx.y;
    int hs = blockIdx.x;
    int q = hs * WS + ws;
    size_t bo = (size_t)q * D1 + c * 9;
    const float* src = fds + ((size_t)b * CM + c) * HS * WS;
#pragma unroll
    for (int i = 0; i < 3; ++i) {
        int rh = refl(hs + i - 1, HS);
#pragma unroll
        for (int j = 0; j < 3; ++j) {
            int rw = refl(ws + j - 1, WS);
            Whi[bo + i * 3 + j] = f2bf(src[rh * WS + rw]);
        }
    }
}

// K5: symmetric bf16 MFMA score GEMM -> bf16 ST (3-buf + frag-read pipelining)
__global__ __launch_bounds__(256, 3) void k_gemm1(float* __restrict__ base,
                                                  const float* __restrict__ g0,
                                                  const float* __restrict__ dg0,
                                                  int b0) {
    __shared__ u16 sA[3][128 * 32], sB[3][128 * 32];   // 48 KB
    int bz = blockIdx.z;
    float* S = base + (size_t)bz * SLOT_F;
    u16* STP = (u16*)S;
    const u16* Whi = (const u16*)(S + STP_F);
    const float* g  = g0  + (size_t)(b0 + bz) * L;
    const float* dg = dg0 + (size_t)(b0 + bz) * L;

    int tid = threadIdx.x;
    int wv = tid >> 6, lane = tid & 63;
    int t0 = blockIdx.x, I = 0;
    while (t0 >= 32 - I) { t0 -= 32 - I; ++I; }
    int J = I + t0;
    int pTile = I * 128, qTile = J * 128;
    int wp = (wv >> 1) * 64, wq = (wv & 1) * 64;
    int r0 = wv * 32;
    int lrow = lane >> 2;
    int csw = ((lane & 3) ^ ((lrow >> 1) & 3)) * 8;
    int fr = lane & 15, fq = lane >> 4;

    const u16* gArow = Whi + (size_t)(pTile + r0 + lrow) * D1 + csw;
    const u16* gBrow = Whi + (size_t)(qTile + r0 + lrow) * D1 + csw;

#define G1STG(kt, bf) do { \
    gll16(gArow + (kt) * 32, &sA[bf][r0 * 32]); \
    gll16(gArow + (kt) * 32 + (size_t)16 * D1, &sA[bf][(r0 + 16) * 32]); \
    gll16(gBrow + (kt) * 32, &sB[bf][r0 * 32]); \
    gll16(gBrow + (kt) * 32 + (size_t)16 * D1, &sB[bf][(r0 + 16) * 32]); } while (0)

#define G1PHASE(t, ca, cb, na, nb_) do { \
    int nxb = ((t) + 1) % 3; \
    _Pragma("unroll") for (int i = 0; i < 4; ++i) \
        nb_[i] = *(const short8v*)&sB[nxb][swz(wq + i * 16 + fr, fq)]; \
    __builtin_amdgcn_s_setprio(1); \
    _Pragma("unroll") for (int mi = 0; mi < 2; ++mi) \
        _Pragma("unroll") for (int ni = 0; ni < 4; ++ni) \
            acc[mi][ni] = __builtin_amdgcn_mfma_f32_16x16x32_bf16(ca[mi], cb[ni], acc[mi][ni], 0, 0, 0); \
    __builtin_amdgcn_s_setprio(0); \
    _Pragma("unroll") for (int i = 0; i < 4; ++i) \
        na[i] = *(const short8v*)&sA[nxb][swz(wp + i * 16 + fr, fq)]; \
    G1STG(((t) + 3 < NT1) ? (t) + 3 : 0, (t) % 3); \
    asm volatile("s_waitcnt vmcnt(4)" ::: "memory"); \
    __builtin_amdgcn_s_setprio(1); \
    _Pragma("unroll") for (int mi = 2; mi < 4; ++mi) \
        _Pragma("unroll") for (int ni = 0; ni < 4; ++ni) \
            acc[mi][ni] = __builtin_amdgcn_mfma_f32_16x16x32_bf16(ca[mi], cb[ni], acc[mi][ni], 0, 0, 0); \
    __builtin_amdgcn_s_setprio(0); \
    asm volatile("s_waitcnt lgkmcnt(0)" ::: "memory"); \
    __builtin_amdgcn_s_barrier(); \
    __builtin_amdgcn_sched_barrier(0); } while (0)

    f32x4 acc[4][4];
#pragma unroll
    for (int mi = 0; mi < 4; ++mi)
#pragma unroll
        for (int ni = 0; ni < 4; ++ni)
#pragma unroll
            for (int r = 0; r < 4; ++r) acc[mi][ni][r] = 0.f;

    G1STG(0, 0);
    G1STG(1, 1);
    G1STG(2, 2);
    asm volatile("s_waitcnt vmcnt(4)" ::: "memory");
    __builtin_amdgcn_s_barrier();
    __builtin_amdgcn_sched_barrier(0);

    short8v fa0[4], fb0[4], fa1[4], fb1[4];
#pragma unroll
    for (int i = 0; i < 4; ++i) {
        fa0[i] = *(const short8v*)&sA[0][swz(wp + i * 16 + fr, fq)];
        fb0[i] = *(const short8v*)&sB[0][swz(wq + i * 16 + fr, fq)];
    }
    asm volatile("s_waitcnt lgkmcnt(0)" ::: "memory");
    __builtin_amdgcn_s_barrier();        // preload reads of buf 0 complete before phase 0 overwrites
    __builtin_amdgcn_sched_barrier(0);

    for (int t = 0; t < NT1; t += 2) {
        G1PHASE(t,     fa0, fb0, fa1, fb1);
        G1PHASE(t + 1, fa1, fb1, fa0, fb0);
    }
#undef G1PHASE
#undef G1STG

#pragma unroll
    for (int ni = 0; ni < 4; ++ni) {
        int qq = qTile + wq + ni * 16 + fr;
        float gq = g[qq];
        float dq = dg[qq];
#pragma unroll
        for (int mi = 0; mi < 4; ++mi) {
            int pB = pTile + wp + mi * 16 + fq * 4;
#pragma unroll
            for (int r = 0; r < 4; ++r) {
                int p = pB + r;
                float v = acc[mi][ni][r] * gq;
                if (p == qq) v += dq;
                STP[(size_t)p * L + qq] = f2bf(v);
            }
        }
    }
    if (I != J) {
#pragma unroll
        for (int mi = 0; mi < 4; ++mi) {
            int p0 = pTile + wp + mi * 16 + fq * 4;
            float gp0 = g[p0], gp1 = g[p0 + 1], gp2 = g[p0 + 2], gp3 = g[p0 + 3];
#pragma unroll
            for (int ni = 0; ni < 4; ++ni) {
                int qq = qTile + wq + ni * 16 + fr;
                u16x4 mv;
                mv[0] = f2bf(acc[mi][ni][0] * gp0);
                mv[1] = f2bf(acc[mi][ni][1] * gp1);
                mv[2] = f2bf(acc[mi][ni][2] * gp2);
                mv[3] = f2bf(acc[mi][ni][3] * gp3);
                *(u16x4*)(STP + (size_t)qq * L + p0) = mv;
            }
        }
    }
}

// K6: per-WAVE softmax (1 row per wave, zero block barriers) -> unnormalized exp
// bf16 + rowsum; exact argmax via fds-stencil refinement (wave-local).
__global__ __launch_bounds__(256) void k_softmax(float* __restrict__ base,
                                                 const float* __restrict__ fds,
                                                 const float* __restrict__ g0,
                                                 const float* __restrict__ dg0,
                                                 float* __restrict__ rowsum,
                                                 float* __restrict__ out1, int b0) {
    __shared__ int candList[4][64];
    __shared__ int candCount[4];
    int bz = blockIdx.y;
    int b  = b0 + bz;
    float* S = base + (size_t)bz * SLOT_F;
    u16* STP = (u16*)S;
    const float* fdsb = fds + (size_t)b * CM * HS * WS;
    const float* g  = g0  + (size_t)b * L;
    const float* dg = dg0 + (size_t)b * L;

    int t = threadIdx.x;
    int lane = t & 63, wv = t >> 6;
    int p = blockIdx.x * 4 + wv;
    u16* rowp = STP + (size_t)p * L;
    if (lane == 0) candCount[wv] = 0;

    // register-cache the wave's row: lane reads vecs j*64+lane (coalesced 1KB/instr)
    short8v v[8];
#pragma unroll
    for (int j = 0; j < 8; ++j) v[j] = ((const short8v*)rowp)[j * 64 + lane];

    float mx = -3.4e38f;
#pragma unroll
    for (int j = 0; j < 8; ++j)
#pragma unroll
        for (int jj = 0; jj < 8; ++jj) mx = fmaxf(mx, bf2f((u16)v[j][jj]));
#pragma unroll
    for (int o = 32; o > 0; o >>= 1) mx = fmaxf(mx, __shfl_xor(mx, o));
    float M = mx;
    float cth = M - (fabsf(M) * 0.0625f + 1e-5f);

    float s = 0.f;
#pragma unroll
    for (int j = 0; j < 8; ++j) {
        short8v o8;
#pragma unroll
        for (int jj = 0; jj < 8; ++jj) {
            float x = bf2f((u16)v[j][jj]);
            if (x >= cth) {
                int ix = atomicAdd(&candCount[wv], 1);
                if (ix < 64) candList[wv][ix] = (j * 64 + lane) * 8 + jj;
            }
            float e = __expf(x - M);
            o8[jj] = (short)f2bf(e);
            s += e;
        }
        ((short8v*)rowp)[j * 64 + lane] = o8;
    }
#pragma unroll
    for (int o = 32; o > 0; o >>= 1) s += __shfl_xor(s, o);
    if (lane == 0) rowsum[(size_t)b * L + p] = s;

    int nc = candCount[wv]; if (nc > 64) nc = 64;
    int bestI;
    if (nc == 1) {
        bestI = candList[wv][0];
    } else {
        float bestE = -3.4e38f; bestI = L;
        int hp = p >> 6, wpp = p & 63;
        for (int k = 0; k < nc; ++k) {
            int cand = candList[wv][k];
            int hc = cand >> 6, wcc = cand & 63;
            float part = 0.f;
#pragma unroll
            for (int e = 0; e < 18; ++e) {   // D1 = 1152 = 18*64, static unroll (rule 20)
                int kk = lane + e * 64;
                int c  = kk / 9, ij = kk - c * 9;
                int di = ij / 3, dj = ij - di * 3;
                float pv = fdsb[(size_t)c * (HS * WS)
                                + refl(hp + di - 1, HS) * WS + refl(wpp + dj - 1, WS)];
                float cv = fdsb[(size_t)c * (HS * WS)
                                + refl(hc + di - 1, HS) * WS + refl(wcc + dj - 1, WS)];
                part += pv * cv;
            }
#pragma unroll
            for (int o = 32; o > 0; o >>= 1) part += __shfl_xor(part, o);
            float e1 = part * g[cand] + (p == cand ? dg[cand] : 0.f);
            if (e1 > bestE || (e1 == bestE && cand < bestI)) { bestE = e1; bestI = cand; }
        }
    }
    if (lane == 0) {
        out1[(size_t)(b * 2 + 0) * L + p] = (float)(bestI / WS - 32);
        out1[(size_t)(b * 2 + 1) * L + p] = (float)(bestI % WS - 32);
    }
}

// K7: At[n',q], n' = (ki*4+kj)*128 + c  (gather-coalesced layout); 4 q per thread
__global__ __launch_bounds__(256) void k_buildA(const float* __restrict__ alpha,
                                                float* __restrict__ base, int b0) {
    int bz = blockIdx.z;
    int b  = b0 + bz;
    u16* At = (u16*)(base + (size_t)bz * SLOT_F + STP_F);
    int q0 = (blockIdx.x * 256 + threadIdx.x) * 4;
    int n  = blockIdx.y;
    int c = n & 127, kikj = n >> 7, ki = kikj >> 2, kj = kikj & 3;
    int hs = q0 >> 6, ws = q0 & 63;
    int rh = refl(2 * hs + ki - 1, H);
    const float* arow = alpha + ((size_t)b * CA + c) * H * W_ + rh * W_;
    u16x4 ov;
#pragma unroll
    for (int j = 0; j < 4; ++j)
        ov[j] = f2bf(arow[refl(2 * (ws + j) + kj - 1, W_)]);
    *(u16x4*)(At + (size_t)n * L + q0) = ov;
}

// K8: 256^2-tile bf16 MFMA paste GEMM, 4-buf counted-vmcnt + frag-read pipelining.
__global__ __launch_bounds__(512, 2) void k_gemm2(float* __restrict__ base) {
    __shared__ u16 smem[65536];   // 128 KB: 4 bufs x 32KB (A 16K + B 16K)
    char* sm = (char*)smem;
    int bz = blockIdx.z;
    float* S = base + (size_t)bz * SLOT_F;
    const u16* P  = (const u16*)S;
    const u16* At = (const u16*)(S + STP_F);
    u16* Z        = (u16*)(S + STP_F + RA_F);

    int tid = threadIdx.x;
    int wid = tid >> 6, lane = tid & 63;
    int wm = wid >> 2, wn = wid & 3;
    int pTile = blockIdx.x * 256, nTile = blockIdx.y * 256;
    int fr = lane & 15, fq = lane >> 4;

    int off0 = wid * 1024 + lane * 16;
    int row0 = off0 >> 6, cb0 = off0 & 63;
    int off1 = off0 + 8192;
    int row1 = off1 >> 6, cb1 = off1 & 63;
    const u16* pA0 = P  + (size_t)(pTile + row0) * L + ((cb0 ^ (((row0 >> 1) & 3) << 4)) >> 1);
    const u16* pA1 = P  + (size_t)(pTile + row1) * L + ((cb1 ^ (((row1 >> 1) & 3) << 4)) >> 1);
    const u16* pB0 = At + (size_t)(nTile + row0) * L + ((cb0 ^ (((row0 >> 1) & 3) << 4)) >> 1);
    const u16* pB1 = At + (size_t)(nTile + row1) * L + ((cb1 ^ (((row1 >> 1) & 3) << 4)) >> 1);

#define STG2(kt, bi) do { \
    char* d = sm + (bi) * 32768 + wid * 1024; \
    gll16(pA0 + (size_t)(kt) * 32, d); \
    gll16(pA1 + (size_t)(kt) * 32, d + 8192); \
    gll16(pB0 + (size_t)(kt) * 32, d + 16384); \
    gll16(pB1 + (size_t)(kt) * 32, d + 24576); } while (0)

#define PRELOAD2(fa, fb, bi) do { \
    const char* Ab_ = sm + (bi) * 32768; \
    const char* Bb_ = Ab_ + 16384; \
    _Pragma("unroll") for (int n = 0; n < 4; ++n) fb[n] = rdfrag32(Bb_, wn * 64 + n * 16 + fr, fq); \
    _Pragma("unroll") for (int m = 0; m < 8; ++m) fa[m] = rdfrag32(Ab_, wm * 128 + m * 16 + fr, fq); } while (0)

#define PHASE2(t, ca, cb, na, nb_) do { \
    const char* Abn = sm + (((t) + 1) & 3) * 32768; \
    const char* Bbn = Abn + 16384; \
    _Pragma("unroll") for (int n = 0; n < 4; ++n) nb_[n] = rdfrag32(Bbn, wn * 64 + n * 16 + fr, fq); \
    __builtin_amdgcn_s_setprio(1); \
    _Pragma("unroll") for (int m = 0; m < 4; ++m) \
        _Pragma("unroll") for (int n = 0; n < 4; ++n) \
            acc[m][n] = __builtin_amdgcn_mfma_f32_16x16x32_bf16(ca[m], cb[n], acc[m][n], 0, 0, 0); \
    __builtin_amdgcn_s_setprio(0); \
    _Pragma("unroll") for (int m = 0; m < 8; ++m) na[m] = rdfrag32(Abn, wm * 128 + m * 16 + fr, fq); \
    STG2(((t) + 3 < NT2) ? (t) + 3 : 0, ((t) + 3) & 3); \
    asm volatile("s_waitcnt vmcnt(4)" ::: "memory"); \
    __builtin_amdgcn_s_setprio(1); \
    _Pragma("unroll") for (int m = 4; m < 8; ++m) \
        _Pragma("unroll") for (int n = 0; n < 4; ++n) \
            acc[m][n] = __builtin_amdgcn_mfma_f32_16x16x32_bf16(ca[m], cb[n], acc[m][n], 0, 0, 0); \
    __builtin_amdgcn_s_setprio(0); \
    asm volatile("s_waitcnt lgkmcnt(0)" ::: "memory"); \
    __builtin_amdgcn_s_barrier(); \
    __builtin_amdgcn_sched_barrier(0); } while (0)

    f32x4 acc[8][4];
#pragma unroll
    for (int m = 0; m < 8; ++m)
#pragma unroll
        for (int n = 0; n < 4; ++n)
#pragma unroll
            for (int r = 0; r < 4; ++r) acc[m][n][r] = 0.f;

    STG2(0, 0);
    STG2(1, 1);
    STG2(2, 2);
    asm volatile("s_waitcnt vmcnt(4)" ::: "memory");
    __builtin_amdgcn_s_barrier();
    __builtin_amdgcn_sched_barrier(0);

    short8v fa0[8], fb0[4], fa1[8], fb1[4];
    PRELOAD2(fa0, fb0, 0);
    asm volatile("s_waitcnt lgkmcnt(0)" ::: "memory");
    __builtin_amdgcn_s_barrier();
    __builtin_amdgcn_sched_barrier(0);

    for (int t = 0; t < NT2; t += 2) {
        PHASE2(t,     fa0, fb0, fa1, fb1);
        PHASE2(t + 1, fa1, fb1, fa0, fb0);
    }
#undef PHASE2
#undef PRELOAD2
#undef STG2

#pragma unroll
    for (int m = 0; m < 8; ++m)
#pragma unroll
        for (int n = 0; n < 4; ++n) {
            int nn = nTile + wn * 64 + n * 16 + fr;
#pragma unroll
            for (int r = 0; r < 4; ++r) {
                int pp = pTile + wm * 128 + m * 16 + fq * 4 + r;
                Z[(size_t)pp * D2 + nn] = f2bf(acc[m][n][r]);
            }
        }
}

// K9: transposed-conv gather -> yt[pix, c] bf16; applies 1/rowsum[src]
__global__ __launch_bounds__(256) void k_gather(float* __restrict__ base,
                                                const float* __restrict__ rowsum,
                                                u16* __restrict__ yt, int b0) {
    int bz = blockIdx.z;
    int b  = b0 + bz;
    const u16* Z = (const u16*)(base + (size_t)bz * SLOT_F + STP_F + RA_F);
    const float* rs = rowsum + (size_t)b * L;
    int c  = threadIdx.x & 127;
    int pl = threadIdx.x >> 7;
    int w  = blockIdx.x * 2 + pl;
    int h  = blockIdx.y;
    float s = 0.f;
#pragma unroll
    for (int ki = 0; ki < 4; ++ki) {
        int num = h + 1 - ki;
        if (num < 0 || (num & 1)) continue;
        int hs = num >> 1;
        if (hs >= HS) continue;
#pragma unroll
        for (int kj = 0; kj < 4; ++kj) {
            int numw = w + 1 - kj;
            if (numw < 0 || (numw & 1)) continue;
            int wsd = numw >> 1;
            if (wsd >= WS) continue;
            int src = hs * WS + wsd;
            s += bf2f(Z[(size_t)src * D2 + (ki * 4 + kj) * 128 + c]) / rs[src];
        }
    }
    int pix = h * W_ + w;
    int cs = c ^ ((pix & 7) << 3);
    yt[((size_t)b * 16384 + pix) * 128 + cs] = f2bf(0.25f * s);
}

__global__ __launch_bounds__(256) void k_cvtww(const float* __restrict__ ww,
                                               u16* __restrict__ wwbf) {
    int i = blockIdx.x * 256 + threadIdx.x;
    int o = i >> 7, c = i & 127;
    wwbf[o * 128 + (c ^ ((o & 7) << 3))] = f2bf(ww[i]);
}

// K10: yw[o, gp] = sum_c w_w[o,c] * y[gp, c]   MFMA, K=128
__global__ __launch_bounds__(256) void k_ywgemm(const u16* __restrict__ wwbf,
                                                const u16* __restrict__ yt,
                                                float* __restrict__ yw) {
    __shared__ u16 sA[128 * 128], sB[128 * 128];
    int tid = threadIdx.x;
    int wv = tid >> 6, lane = tid & 63;
    int nTile = blockIdx.x * 128;
    int wp = (wv >> 1) * 64, wn = (wv & 1) * 64;
    int fr = lane & 15, fq = lane >> 4;

    const u16* gB = yt + (size_t)nTile * 128;
#pragma unroll
    for (int i = 0; i < 8; ++i) {
        int o = (i * 4 + wv) * 512;
        gll16(wwbf + o + lane * 8, &sA[o]);
        gll16(gB + o + lane * 8, &sB[o]);
    }
    __syncthreads();

    f32x4 acc[4][4];
#pragma unroll
    for (int mi = 0; mi < 4; ++mi)
#pragma unroll
        for (int ni = 0; ni < 4; ++ni)
#pragma unroll
            for (int r = 0; r < 4; ++r) acc[mi][ni][r] = 0.f;

#pragma unroll
    for (int ks = 0; ks < 4; ++ks) {
        int k0 = ks * 32 + fq * 8;
        short8v a[4], bb[4];
#pragma unroll
        for (int i = 0; i < 4; ++i) {
            int ra = wp + i * 16 + fr;
            a[i] = *(const short8v*)&sA[ra * 128 + (k0 ^ ((ra & 7) << 3))];
            int rb = wn + i * 16 + fr;
            bb[i] = *(const short8v*)&sB[rb * 128 + (k0 ^ ((rb & 7) << 3))];
        }
#pragma unroll
        for (int mi = 0; mi < 4; ++mi)
#pragma unroll
            for (int ni = 0; ni < 4; ++ni)
                acc[mi][ni] = __builtin_amdgcn_mfma_f32_16x16x32_bf16(a[mi], bb[ni], acc[mi][ni], 0, 0, 0);
    }

#pragma unroll
    for (int mi = 0; mi < 4; ++mi)
#pragma unroll
        for (int ni = 0; ni < 4; ++ni) {
            int gp = nTile + wn + ni * 16 + fr;
#pragma unroll
            for (int r = 0; r < 4; ++r) {
                int o = wp + mi * 16 + fq * 4 + r;
                yw[(size_t)o * NPIX + gp] = acc[mi][ni][r];
            }
        }
}

__global__ __launch_bounds__(256) void k_stats(const float* __restrict__ yw,
                                               float* __restrict__ meanvar) {
    int o = blockIdx.x, t = threadIdx.x;
    __shared__ float rs[256], rq[256];
    float s = 0.f, q = 0.f;
    const float* p = yw + (size_t)o * NPIX;
    for (int i = t; i < NPIX; i += 256) {
        float v = p[i];
        s += v;
        q += v * v;
    }
    rs[t] = s; rq[t] = q;
    __syncthreads();
    for (int off = 128; off > 0; off >>= 1) {
        if (t < off) { rs[t] += rs[t + off]; rq[t] += rq[t + off]; }
        __syncthreads();
    }
    if (t == 0) {
        float n = (float)NPIX;
        float mean = rs[0] / n;
        float var  = rq[0] / n - mean * mean;
        meanvar[o] = mean;
        meanvar[CA + o] = var;
    }
}

__global__ __launch_bounds__(256) void k_final(const float* __restrict__ yw,
                                               const float* __restrict__ meanvar,
                                               const float* __restrict__ gamma,
                                               const float* __restrict__ beta,
                                               const float* __restrict__ alpha,
                                               float* __restrict__ out0) {
    size_t i = ((size_t)blockIdx.x * 256 + threadIdx.x) * 4;
    int c = (int)((i >> 14) & 127);
    int b = (int)(i >> 21);
    int pix = (int)(i & 16383);
    float4 v = *(const float4*)(yw + (size_t)c * NPIX + b * 16384 + pix);
    float4 a = *(const float4*)(alpha + i);
    float mean = meanvar[c];
    float var  = meanvar[CA + c];
    float sc   = rsqrtf(var + 1e-5f) * gamma[c];
    float bt   = beta[c];
    float4 r;
    r.x = (v.x - mean) * sc + bt + a.x;
    r.y = (v.y - mean) * sc + bt + a.y;
    r.z = (v.z - mean) * sc + bt + a.z;
    r.w = (v.w - mean) * sc + bt + a.w;
    *(float4*)(out0 + i) = r;
}

extern "C" void kernel_launch(void* const* d_in, const int* in_sizes, int n_in,
                              void* d_out, int out_size, void* d_ws, size_t ws_size,
                              hipStream_t stream) {
    (void)in_sizes; (void)n_in; (void)out_size;
    const float* f     = (const float*)d_in[0];
    const float* alpha = (const float*)d_in[1];
    const float* unk   = (const float*)d_in[2];
    const float* gw    = (const float*)d_in[3];
    const float* gb    = (const float*)d_in[4];
    const float* ww    = (const float*)d_in[5];
    const float* gamma = (const float*)d_in[6];
    const float* beta  = (const float*)d_in[7];

    float* out0 = (float*)d_out;
    float* out1 = out0 + (size_t)B * CA * H * W_;
    float* out2 = out1 + (size_t)B * 2 * HS * WS;

    // ---- persistent region ----
    float* wsf = (float*)d_ws;
    size_t off = 0;
    float* fds     = wsf + off; off += (size_t)B * CM * HS * WS;
    float* ssq     = wsf + off; off += (size_t)B * HS * WS;
    float* gbuf    = wsf + off; off += (size_t)B * L;
    float* dgbuf   = wsf + off; off += (size_t)B * L;
    float* suk     = wsf + off; off += 64;
    float* ytF     = wsf + off; off += (size_t)NPIX * 128 / 2;
    float* wwbfF   = wsf + off; off += 8192;
    float* meanvar = wsf + off; off += 256;
    float* rowsum  = wsf + off; off += (size_t)B * L;
    float* base    = wsf + off;

    const size_t PRE_F = off;
    // nb even only: gemm2 grid 16*8*nb must be a multiple of 256 CUs (R15 lesson).
    int nb = (ws_size >= (PRE_F + 4 * SLOT_F) * sizeof(float)) ? 4 : 2;

    float* yw   = base;
    u16*   yt   = (u16*)ytF;
    u16*   wwbf = (u16*)wwbfF;

    k_cvtww<<<64, 256, 0, stream>>>(ww, wwbf);
    k_conv_ds<<<dim3(64, 4), 256, 0, stream>>>(f, gw, gb, fds, ssq);
    k_scale<<<4, 256, 0, stream>>>(unk, suk, out2);
    k_gate<<<dim3(64, 4), 64, 0, stream>>>(unk, ssq, suk, gbuf, dgbuf);

    for (int b0 = 0; b0 < B; b0 += nb) {
        k_buildW<<<dim3(64, 32, nb), dim3(64, 4), 0, stream>>>(fds, base, b0);
        k_gemm1<<<dim3(528, 1, nb), 256, 0, stream>>>(base, gbuf, dgbuf, b0);
        k_softmax<<<dim3(1024, nb), 256, 0, stream>>>(base, fds, gbuf, dgbuf, rowsum, out1, b0);
        k_buildA<<<dim3(4, 2048, nb), 256, 0, stream>>>(alpha, base, b0);
        k_gemm2<<<dim3(16, 8, nb), 512, 0, stream>>>(base);
        k_gather<<<dim3(64, 128, nb), 256, 0, stream>>>(base, rowsum, yt, b0);
    }

    k_ywgemm<<<512, 256, 0, stream>>>(wwbf, yt, yw);
    k_stats<<<128, 256, 0, stream>>>(yw, meanvar);
    k_final<<<8192, 256, 0, stream>>>(yw, meanvar, gamma, beta, alpha, out0);
}

// Round 19
// 793.039 us; speedup vs baseline: 1.0445x; 1.0445x over previous
//
#include <hip/hip_runtime.h>
#include <math.h>

#define B 4
#define CG 256
#define CM 128
#define CA 128
#define H 128
#define W_ 128
#define HS 64
#define WS 64
#define L 4096
#define D1 1152
#define D2 2048
#define NPIX 65536
#define NT1 36
#define NT2 128

// slot layout (floats): [STP bf16 L*L][RA: Whi bf16 -> At bf16][RB: Z bf16]
#define STP_F 8388608UL
#define RA_F  4194304UL
#define SLOT_F (STP_F + RA_F + RA_F)   // 16,777,216 floats = 67.1 MB

typedef unsigned short u16;
typedef __attribute__((ext_vector_type(8))) short short8v;
typedef __attribute__((ext_vector_type(4))) unsigned short u16x4;
typedef __attribute__((ext_vector_type(4))) float f32x4;

__device__ __forceinline__ float bf2f(u16 x) {
    union { unsigned int u; float f; } v; v.u = ((unsigned int)x) << 16; return v.f;
}
__device__ __forceinline__ u16 f2bf(float x) {
    union { float f; unsigned int u; } v; v.f = x;
    unsigned int r = (v.u + 0x7FFFu + ((v.u >> 16) & 1u)) >> 16;
    return (u16)r;
}
__device__ __forceinline__ void gll16(const void* g, void* l) {
    __builtin_amdgcn_global_load_lds((const __attribute__((address_space(1))) void*)g,
                                     (__attribute__((address_space(3))) void*)l, 16, 0, 0);
}
__device__ __forceinline__ int refl(int i, int n) {
    return i < 0 ? -i : (i >= n ? 2 * n - 2 - i : i);
}
// swizzled LDS element offset for [128][32 u16] tiles (gemm1; 0-conflict per R5)
__device__ __forceinline__ int swz(int row, int fq) {
    return row * 32 + ((fq ^ ((row >> 1) & 3)) * 8);
}
// gemm2 [256][32 u16] tiles, 64B rows, (r>>1)&3 chunk-XOR (0-conflict per R9)
__device__ __forceinline__ short8v rdfrag32(const char* lds, int r, int fq) {
    return *(const short8v*)(lds + r * 64 + ((fq * 16) ^ (((r >> 1) & 3) << 4)));
}

// K0: f_ds = 1x1 conv at even pixels + fused ssq
__global__ __launch_bounds__(256) void k_conv_ds(const float* __restrict__ f,
                                                 const float* __restrict__ gw,
                                                 const float* __restrict__ gb,
                                                 float* __restrict__ fds,
                                                 float* __restrict__ ssq) {
    __shared__ float sf[CG * 64];
    __shared__ float part[4][64];
    int t = threadIdx.x;
    int hs = blockIdx.x, b = blockIdx.y;
    const float* fb = f + (size_t)b * CG * H * W_ + (2 * hs) * W_;
    for (int idx = t; idx < CG * 64; idx += 256) {
        int ci = idx >> 6, ws = idx & 63;
        sf[idx] = fb[(size_t)ci * H * W_ + 2 * ws];
    }
    __syncthreads();
    int ws = t & 63;
    int wave = __builtin_amdgcn_readfirstlane(t >> 6);
    const float* gwp = gw + (size_t)(wave * 32) * CG;
    float acc[32];
#pragma unroll
    for (int r = 0; r < 32; ++r) acc[r] = gb[wave * 32 + r];
    for (int ci = 0; ci < CG; ++ci) {
        float fv = sf[ci * 64 + ws];
#pragma unroll
        for (int r = 0; r < 32; ++r) acc[r] += gwp[r * CG + ci] * fv;
    }
    float sq = 0.f;
#pragma unroll
    for (int r = 0; r < 32; ++r) {
        int co = wave * 32 + r;
        fds[(((size_t)b * CM + co) * HS + hs) * WS + ws] = acc[r];
        sq += acc[r] * acc[r];
    }
    part[wave][ws] = sq;
    __syncthreads();
    if (t < 64)
        ssq[((size_t)b * HS + hs) * WS + t] =
            part[0][t] + part[1][t] + part[2][t] + part[3][t];
}

__global__ __launch_bounds__(256) void k_scale(const float* __restrict__ unk,
                                               float* __restrict__ suk,
                                               float* __restrict__ out2) {
    int b = blockIdx.x, t = threadIdx.x;
    __shared__ float red[256];
    float s = 0.f;
    for (int i = t; i < L; i += 256) {
        int hs = i >> 6, ws = i & 63;
        s += unk[(size_t)b * H * W_ + (2 * hs) * W_ + 2 * ws];
    }
    red[t] = s;
    __syncthreads();
    for (int o = 128; o > 0; o >>= 1) {
        if (t < o) red[t] += red[t + o];
        __syncthreads();
    }
    if (t == 0) {
        float u = red[0] / (float)L;
        float k = 1.0f - u;
        float su = sqrtf(u / k); su = fminf(fmaxf(su, 0.1f), 10.0f);
        float sk = sqrtf(k / u); sk = fminf(fmaxf(sk, 0.1f), 10.0f);
        suk[b * 2] = su; suk[b * 2 + 1] = sk;
        out2[b * 2] = su; out2[b * 2 + 1] = sk;
    }
}

__global__ __launch_bounds__(64) void k_gate(const float* __restrict__ unk,
                                             const float* __restrict__ ssq,
                                             const float* __restrict__ suk,
                                             float* __restrict__ g,
                                             float* __restrict__ dg) {
    int ws = threadIdx.x, hs = blockIdx.x, b = blockIdx.y;
    float sm = 0.f, sq = 0.f;
    for (int di = -1; di <= 1; ++di) {
        int rh = refl(hs + di, HS);
        for (int dj = -1; dj <= 1; ++dj) {
            int rw = refl(ws + dj, WS);
            sm += unk[(size_t)b * H * W_ + (2 * rh) * W_ + 2 * rw];
            sq += ssq[((size_t)b * HS + rh) * WS + rw];
        }
    }
    float mm   = (sm > 0.0f) ? 1.0f : 0.0f;
    float norm = sqrtf(sq);
    float gate = (mm > 0.0f) ? suk[2 * b] : suk[2 * b + 1];
    int q = hs * WS + ws;
    g[(size_t)b * L + q]  = gate / fmaxf(norm, 1e-4f);
    dg[(size_t)b * L + q] = -10000.0f * mm;
}

// K4: bf16 W (lanes over ws, broadcast reads — A/B proven form)
__global__ __launch_bounds__(256) void k_buildW(const float* __restrict__ fds,
                                                float* __restrict__ base, int b0) {
    int bz = blockIdx.z;
    int b  = b0 + bz;
    u16* Whi = (u16*)(base + (size_t)bz * SLOT_F + STP_F);
    int ws = threadIdx.x;
    int c  = blockIdx.y * 4 + threadIdx.y;
    int hs = blockIdx.x;
    int q = hs * WS + ws;
    size_t bo = (size_t)q * D1 + c * 9;
    const float* src = fds + ((size_t)b * CM + c) * HS * WS;
#pragma unroll
    for (int i = 0; i < 3; ++i) {
        int rh = refl(hs + i - 1, HS);
#pragma unroll
        for (int j = 0; j < 3; ++j) {
            int rw = refl(ws + j - 1, WS);
            Whi[bo + i * 3 + j] = f2bf(src[rh * WS + rw]);
        }
    }
}

// K5: symmetric bf16 MFMA score GEMM -> bf16 ST (3-buf + frag-read pipelining)
__global__ __launch_bounds__(256, 3) void k_gemm1(float* __restrict__ base,
                                                  const float* __restrict__ g0,
                                                  const float* __restrict__ dg0,
                                                  int b0) {
    __shared__ u16 sA[3][128 * 32], sB[3][128 * 32];   // 48 KB
    int bz = blockIdx.z;
    float* S = base + (size_t)bz * SLOT_F;
    u16* STP = (u16*)S;
    const u16* Whi = (const u16*)(S + STP_F);
    const float* g  = g0  + (size_t)(b0 + bz) * L;
    const float* dg = dg0 + (size_t)(b0 + bz) * L;

    int tid = threadIdx.x;
    int wv = tid >> 6, lane = tid & 63;
    int t0 = blockIdx.x, I = 0;
    while (t0 >= 32 - I) { t0 -= 32 - I; ++I; }
    int J = I + t0;
    int pTile = I * 128, qTile = J * 128;
    int wp = (wv >> 1) * 64, wq = (wv & 1) * 64;
    int r0 = wv * 32;
    int lrow = lane >> 2;
    int csw = ((lane & 3) ^ ((lrow >> 1) & 3)) * 8;
    int fr = lane & 15, fq = lane >> 4;

    const u16* gArow = Whi + (size_t)(pTile + r0 + lrow) * D1 + csw;
    const u16* gBrow = Whi + (size_t)(qTile + r0 + lrow) * D1 + csw;

#define G1STG(kt, bf) do { \
    gll16(gArow + (kt) * 32, &sA[bf][r0 * 32]); \
    gll16(gArow + (kt) * 32 + (size_t)16 * D1, &sA[bf][(r0 + 16) * 32]); \
    gll16(gBrow + (kt) * 32, &sB[bf][r0 * 32]); \
    gll16(gBrow + (kt) * 32 + (size_t)16 * D1, &sB[bf][(r0 + 16) * 32]); } while (0)

#define G1PHASE(t, ca, cb, na, nb_) do { \
    int nxb = ((t) + 1) % 3; \
    _Pragma("unroll") for (int i = 0; i < 4; ++i) \
        nb_[i] = *(const short8v*)&sB[nxb][swz(wq + i * 16 + fr, fq)]; \
    __builtin_amdgcn_s_setprio(1); \
    _Pragma("unroll") for (int mi = 0; mi < 2; ++mi) \
        _Pragma("unroll") for (int ni = 0; ni < 4; ++ni) \
            acc[mi][ni] = __builtin_amdgcn_mfma_f32_16x16x32_bf16(ca[mi], cb[ni], acc[mi][ni], 0, 0, 0); \
    __builtin_amdgcn_s_setprio(0); \
    _Pragma("unroll") for (int i = 0; i < 4; ++i) \
        na[i] = *(const short8v*)&sA[nxb][swz(wp + i * 16 + fr, fq)]; \
    G1STG(((t) + 3 < NT1) ? (t) + 3 : 0, (t) % 3); \
    asm volatile("s_waitcnt vmcnt(4)" ::: "memory"); \
    __builtin_amdgcn_s_setprio(1); \
    _Pragma("unroll") for (int mi = 2; mi < 4; ++mi) \
        _Pragma("unroll") for (int ni = 0; ni < 4; ++ni) \
            acc[mi][ni] = __builtin_amdgcn_mfma_f32_16x16x32_bf16(ca[mi], cb[ni], acc[mi][ni], 0, 0, 0); \
    __builtin_amdgcn_s_setprio(0); \
    asm volatile("s_waitcnt lgkmcnt(0)" ::: "memory"); \
    __builtin_amdgcn_s_barrier(); \
    __builtin_amdgcn_sched_barrier(0); } while (0)

    f32x4 acc[4][4];
#pragma unroll
    for (int mi = 0; mi < 4; ++mi)
#pragma unroll
        for (int ni = 0; ni < 4; ++ni)
#pragma unroll
            for (int r = 0; r < 4; ++r) acc[mi][ni][r] = 0.f;

    G1STG(0, 0);
    G1STG(1, 1);
    G1STG(2, 2);
    asm volatile("s_waitcnt vmcnt(4)" ::: "memory");
    __builtin_amdgcn_s_barrier();
    __builtin_amdgcn_sched_barrier(0);

    short8v fa0[4], fb0[4], fa1[4], fb1[4];
#pragma unroll
    for (int i = 0; i < 4; ++i) {
        fa0[i] = *(const short8v*)&sA[0][swz(wp + i * 16 + fr, fq)];
        fb0[i] = *(const short8v*)&sB[0][swz(wq + i * 16 + fr, fq)];
    }
    asm volatile("s_waitcnt lgkmcnt(0)" ::: "memory");
    __builtin_amdgcn_s_barrier();        // preload reads of buf 0 complete before phase 0 overwrites
    __builtin_amdgcn_sched_barrier(0);

    for (int t = 0; t < NT1; t += 2) {
        G1PHASE(t,     fa0, fb0, fa1, fb1);
        G1PHASE(t + 1, fa1, fb1, fa0, fb0);
    }
#undef G1PHASE
#undef G1STG

#pragma unroll
    for (int ni = 0; ni < 4; ++ni) {
        int qq = qTile + wq + ni * 16 + fr;
        float gq = g[qq];
        float dq = dg[qq];
#pragma unroll
        for (int mi = 0; mi < 4; ++mi) {
            int pB = pTile + wp + mi * 16 + fq * 4;
#pragma unroll
            for (int r = 0; r < 4; ++r) {
                int p = pB + r;
                float v = acc[mi][ni][r] * gq;
                if (p == qq) v += dq;
                STP[(size_t)p * L + qq] = f2bf(v);
            }
        }
    }
    if (I != J) {
#pragma unroll
        for (int mi = 0; mi < 4; ++mi) {
            int p0 = pTile + wp + mi * 16 + fq * 4;
            float gp0 = g[p0], gp1 = g[p0 + 1], gp2 = g[p0 + 2], gp3 = g[p0 + 3];
#pragma unroll
            for (int ni = 0; ni < 4; ++ni) {
                int qq = qTile + wq + ni * 16 + fr;
                u16x4 mv;
                mv[0] = f2bf(acc[mi][ni][0] * gp0);
                mv[1] = f2bf(acc[mi][ni][1] * gp1);
                mv[2] = f2bf(acc[mi][ni][2] * gp2);
                mv[3] = f2bf(acc[mi][ni][3] * gp3);
                *(u16x4*)(STP + (size_t)qq * L + p0) = mv;
            }
        }
    }
}

// K6: softmax (register-cached row, R17 form) -> unnormalized exp bf16 + 1/rowsum.
__global__ __launch_bounds__(256) void k_softmax(float* __restrict__ base,
                                                 const float* __restrict__ fds,
                                                 const float* __restrict__ g0,
                                                 const float* __restrict__ dg0,
                                                 float* __restrict__ rowinv,
                                                 float* __restrict__ out1, int b0) {
    __shared__ float wmax[4], wsum[4], cred[4];
    __shared__ int candList[128];
    __shared__ int candCount;
    int bz = blockIdx.y;
    int b  = b0 + bz;
    float* S = base + (size_t)bz * SLOT_F;
    u16* STP = (u16*)S;
    const float* fdsb = fds + (size_t)b * CM * HS * WS;
    const float* g  = g0  + (size_t)b * L;
    const float* dg = dg0 + (size_t)b * L;

    int p = blockIdx.x, t = threadIdx.x;
    int lane = t & 63, wv = t >> 6;
    u16* rowp = STP + (size_t)p * L;

    if (t == 0) candCount = 0;
    // register-cache the thread's 16 row elements (2x short8v)
    short8v v0 = ((const short8v*)rowp)[t];
    short8v v1 = ((const short8v*)rowp)[t + 256];
    float mx = -3.4e38f;
#pragma unroll
    for (int j = 0; j < 8; ++j) {
        mx = fmaxf(mx, bf2f((u16)v0[j]));
        mx = fmaxf(mx, bf2f((u16)v1[j]));
    }
#pragma unroll
    for (int o = 32; o > 0; o >>= 1) mx = fmaxf(mx, __shfl_xor(mx, o));
    if (lane == 0) wmax[wv] = mx;
    __syncthreads();
    float M = fmaxf(fmaxf(wmax[0], wmax[1]), fmaxf(wmax[2], wmax[3]));
    float cth = M - (fabsf(M) * 0.0625f + 1e-5f);

    float s = 0.f;
    short8v o0, o1;
#pragma unroll
    for (int j = 0; j < 8; ++j) {
        float v = bf2f((u16)v0[j]);
        if (v >= cth) {
            int ix = atomicAdd(&candCount, 1);
            if (ix < 128) candList[ix] = t * 8 + j;
        }
        float e = __expf(v - M);
        o0[j] = (short)f2bf(e);
        s += e;
    }
#pragma unroll
    for (int j = 0; j < 8; ++j) {
        float v = bf2f((u16)v1[j]);
        if (v >= cth) {
            int ix = atomicAdd(&candCount, 1);
            if (ix < 128) candList[ix] = (t + 256) * 8 + j;
        }
        float e = __expf(v - M);
        o1[j] = (short)f2bf(e);
        s += e;
    }
    ((short8v*)rowp)[t]       = o0;
    ((short8v*)rowp)[t + 256] = o1;
#pragma unroll
    for (int o = 32; o > 0; o >>= 1) s += __shfl_xor(s, o);
    if (lane == 0) wsum[wv] = s;
    __syncthreads();
    if (t == 0) rowinv[(size_t)b * L + p] = 1.0f / (wsum[0] + wsum[1] + wsum[2] + wsum[3]);

    int nc = candCount; if (nc > 128) nc = 128;
    int bestI;
    if (nc == 1) {
        bestI = candList[0];
    } else {
        float bestE = -3.4e38f; bestI = L;
        int hp = p >> 6, wpp = p & 63;
        for (int k = 0; k < nc; ++k) {
            int cand = candList[k];
            int hc = cand >> 6, wcc = cand & 63;
            float part = 0.f;
#pragma unroll
            for (int e = 0; e < 5; ++e) {   // static unroll: rule 20
                int kk = t + e * 256;
                if (kk < D1) {
                    int c  = kk / 9, ij = kk - c * 9;
                    int di = ij / 3, dj = ij - di * 3;
                    float pv = fdsb[(size_t)c * (HS * WS)
                                    + refl(hp + di - 1, HS) * WS + refl(wpp + dj - 1, WS)];
                    float cv = fdsb[(size_t)c * (HS * WS)
                                    + refl(hc + di - 1, HS) * WS + refl(wcc + dj - 1, WS)];
                    part += pv * cv;
                }
            }
#pragma unroll
            for (int o = 32; o > 0; o >>= 1) part += __shfl_xor(part, o);
            if (lane == 0) cred[wv] = part;
            __syncthreads();
            float e1 = (cred[0] + cred[1] + cred[2] + cred[3]) * g[cand]
                     + (p == cand ? dg[cand] : 0.f);
            if (e1 > bestE || (e1 == bestE && cand < bestI)) { bestE = e1; bestI = cand; }
            __syncthreads();
        }
    }
    if (t == 0) {
        out1[(size_t)(b * 2 + 0) * L + p] = (float)(bestI / WS - 32);
        out1[(size_t)(b * 2 + 1) * L + p] = (float)(bestI % WS - 32);
    }
}

// K7: At[n',q], n' = (ki*4+kj)*128 + c  (gather-coalesced layout); 4 q per thread
__global__ __launch_bounds__(256) void k_buildA(const float* __restrict__ alpha,
                                                float* __restrict__ base, int b0) {
    int bz = blockIdx.z;
    int b  = b0 + bz;
    u16* At = (u16*)(base + (size_t)bz * SLOT_F + STP_F);
    int q0 = (blockIdx.x * 256 + threadIdx.x) * 4;
    int n  = blockIdx.y;
    int c = n & 127, kikj = n >> 7, ki = kikj >> 2, kj = kikj & 3;
    int hs = q0 >> 6, ws = q0 & 63;
    int rh = refl(2 * hs + ki - 1, H);
    const float* arow = alpha + ((size_t)b * CA + c) * H * W_ + rh * W_;
    u16x4 ov;
#pragma unroll
    for (int j = 0; j < 4; ++j)
        ov[j] = f2bf(arow[refl(2 * (ws + j) + kj - 1, W_)]);
    *(u16x4*)(At + (size_t)n * L + q0) = ov;
}

// K8: 256^2-tile bf16 MFMA paste GEMM, 4-buf counted-vmcnt + frag-read pipelining.
__global__ __launch_bounds__(512, 2) void k_gemm2(float* __restrict__ base) {
    __shared__ u16 smem[65536];   // 128 KB: 4 bufs x 32KB (A 16K + B 16K)
    char* sm = (char*)smem;
    int bz = blockIdx.z;
    float* S = base + (size_t)bz * SLOT_F;
    const u16* P  = (const u16*)S;
    const u16* At = (const u16*)(S + STP_F);
    u16* Z        = (u16*)(S + STP_F + RA_F);

    int tid = threadIdx.x;
    int wid = tid >> 6, lane = tid & 63;
    int wm = wid >> 2, wn = wid & 3;
    int pTile = blockIdx.x * 256, nTile = blockIdx.y * 256;
    int fr = lane & 15, fq = lane >> 4;

    int off0 = wid * 1024 + lane * 16;
    int row0 = off0 >> 6, cb0 = off0 & 63;
    int off1 = off0 + 8192;
    int row1 = off1 >> 6, cb1 = off1 & 63;
    const u16* pA0 = P  + (size_t)(pTile + row0) * L + ((cb0 ^ (((row0 >> 1) & 3) << 4)) >> 1);
    const u16* pA1 = P  + (size_t)(pTile + row1) * L + ((cb1 ^ (((row1 >> 1) & 3) << 4)) >> 1);
    const u16* pB0 = At + (size_t)(nTile + row0) * L + ((cb0 ^ (((row0 >> 1) & 3) << 4)) >> 1);
    const u16* pB1 = At + (size_t)(nTile + row1) * L + ((cb1 ^ (((row1 >> 1) & 3) << 4)) >> 1);

#define STG2(kt, bi) do { \
    char* d = sm + (bi) * 32768 + wid * 1024; \
    gll16(pA0 + (size_t)(kt) * 32, d); \
    gll16(pA1 + (size_t)(kt) * 32, d + 8192); \
    gll16(pB0 + (size_t)(kt) * 32, d + 16384); \
    gll16(pB1 + (size_t)(kt) * 32, d + 24576); } while (0)

#define PRELOAD2(fa, fb, bi) do { \
    const char* Ab_ = sm + (bi) * 32768; \
    const char* Bb_ = Ab_ + 16384; \
    _Pragma("unroll") for (int n = 0; n < 4; ++n) fb[n] = rdfrag32(Bb_, wn * 64 + n * 16 + fr, fq); \
    _Pragma("unroll") for (int m = 0; m < 8; ++m) fa[m] = rdfrag32(Ab_, wm * 128 + m * 16 + fr, fq); } while (0)

#define PHASE2(t, ca, cb, na, nb_) do { \
    const char* Abn = sm + (((t) + 1) & 3) * 32768; \
    const char* Bbn = Abn + 16384; \
    _Pragma("unroll") for (int n = 0; n < 4; ++n) nb_[n] = rdfrag32(Bbn, wn * 64 + n * 16 + fr, fq); \
    __builtin_amdgcn_s_setprio(1); \
    _Pragma("unroll") for (int m = 0; m < 4; ++m) \
        _Pragma("unroll") for (int n = 0; n < 4; ++n) \
            acc[m][n] = __builtin_amdgcn_mfma_f32_16x16x32_bf16(ca[m], cb[n], acc[m][n], 0, 0, 0); \
    __builtin_amdgcn_s_setprio(0); \
    _Pragma("unroll") for (int m = 0; m < 8; ++m) na[m] = rdfrag32(Abn, wm * 128 + m * 16 + fr, fq); \
    STG2(((t) + 3 < NT2) ? (t) + 3 : 0, ((t) + 3) & 3); \
    asm volatile("s_waitcnt vmcnt(4)" ::: "memory"); \
    __builtin_amdgcn_s_setprio(1); \
    _Pragma("unroll") for (int m = 4; m < 8; ++m) \
        _Pragma("unroll") for (int n = 0; n < 4; ++n) \
            acc[m][n] = __builtin_amdgcn_mfma_f32_16x16x32_bf16(ca[m], cb[n], acc[m][n], 0, 0, 0); \
    __builtin_amdgcn_s_setprio(0); \
    asm volatile("s_waitcnt lgkmcnt(0)" ::: "memory"); \
    __builtin_amdgcn_s_barrier(); \
    __builtin_amdgcn_sched_barrier(0); } while (0)

    f32x4 acc[8][4];
#pragma unroll
    for (int m = 0; m < 8; ++m)
#pragma unroll
        for (int n = 0; n < 4; ++n)
#pragma unroll
            for (int r = 0; r < 4; ++r) acc[m][n][r] = 0.f;

    STG2(0, 0);
    STG2(1, 1);
    STG2(2, 2);
    asm volatile("s_waitcnt vmcnt(4)" ::: "memory");
    __builtin_amdgcn_s_barrier();
    __builtin_amdgcn_sched_barrier(0);

    short8v fa0[8], fb0[4], fa1[8], fb1[4];
    PRELOAD2(fa0, fb0, 0);
    asm volatile("s_waitcnt lgkmcnt(0)" ::: "memory");
    __builtin_amdgcn_s_barrier();
    __builtin_amdgcn_sched_barrier(0);

    for (int t = 0; t < NT2; t += 2) {
        PHASE2(t,     fa0, fb0, fa1, fb1);
        PHASE2(t + 1, fa1, fb1, fa0, fb0);
    }
#undef PHASE2
#undef PRELOAD2
#undef STG2

#pragma unroll
    for (int m = 0; m < 8; ++m)
#pragma unroll
        for (int n = 0; n < 4; ++n) {
            int nn = nTile + wn * 64 + n * 16 + fr;
#pragma unroll
            for (int r = 0; r < 4; ++r) {
                int pp = pTile + wm * 128 + m * 16 + fq * 4 + r;
                Z[(size_t)pp * D2 + nn] = f2bf(acc[m][n][r]);
            }
        }
}

// K9: transposed-conv gather -> yt[pix, c] bf16; multiplies by rowinv[src]
__global__ __launch_bounds__(256) void k_gather(float* __restrict__ base,
                                                const float* __restrict__ rowinv,
                                                u16* __restrict__ yt, int b0) {
    int bz = blockIdx.z;
    int b  = b0 + bz;
    const u16* Z = (const u16*)(base + (size_t)bz * SLOT_F + STP_F + RA_F);
    const float* rs = rowinv + (size_t)b * L;
    int c  = threadIdx.x & 127;
    int pl = threadIdx.x >> 7;
    int w  = blockIdx.x * 2 + pl;
    int h  = blockIdx.y;
    float s = 0.f;
#pragma unroll
    for (int ki = 0; ki < 4; ++ki) {
        int num = h + 1 - ki;
        if (num < 0 || (num & 1)) continue;
        int hs = num >> 1;
        if (hs >= HS) continue;
#pragma unroll
        for (int kj = 0; kj < 4; ++kj) {
            int numw = w + 1 - kj;
            if (numw < 0 || (numw & 1)) continue;
            int wsd = numw >> 1;
            if (wsd >= WS) continue;
            int src = hs * WS + wsd;
            s += bf2f(Z[(size_t)src * D2 + (ki * 4 + kj) * 128 + c]) * rs[src];
        }
    }
    int pix = h * W_ + w;
    int cs = c ^ ((pix & 7) << 3);
    yt[((size_t)b * 16384 + pix) * 128 + cs] = f2bf(0.25f * s);
}

__global__ __launch_bounds__(256) void k_cvtww(const float* __restrict__ ww,
                                               u16* __restrict__ wwbf) {
    int i = blockIdx.x * 256 + threadIdx.x;
    int o = i >> 7, c = i & 127;
    wwbf[o * 128 + (c ^ ((o & 7) << 3))] = f2bf(ww[i]);
}

// K10: yw[o, gp] = sum_c w_w[o,c] * y[gp, c]   MFMA, K=128
__global__ __launch_bounds__(256) void k_ywgemm(const u16* __restrict__ wwbf,
                                                const u16* __restrict__ yt,
                                                float* __restrict__ yw) {
    __shared__ u16 sA[128 * 128], sB[128 * 128];
    int tid = threadIdx.x;
    int wv = tid >> 6, lane = tid & 63;
    int nTile = blockIdx.x * 128;
    int wp = (wv >> 1) * 64, wn = (wv & 1) * 64;
    int fr = lane & 15, fq = lane >> 4;

    const u16* gB = yt + (size_t)nTile * 128;
#pragma unroll
    for (int i = 0; i < 8; ++i) {
        int o = (i * 4 + wv) * 512;
        gll16(wwbf + o + lane * 8, &sA[o]);
        gll16(gB + o + lane * 8, &sB[o]);
    }
    __syncthreads();

    f32x4 acc[4][4];
#pragma unroll
    for (int mi = 0; mi < 4; ++mi)
#pragma unroll
        for (int ni = 0; ni < 4; ++ni)
#pragma unroll
            for (int r = 0; r < 4; ++r) acc[mi][ni][r] = 0.f;

#pragma unroll
    for (int ks = 0; ks < 4; ++ks) {
        int k0 = ks * 32 + fq * 8;
        short8v a[4], bb[4];
#pragma unroll
        for (int i = 0; i < 4; ++i) {
            int ra = wp + i * 16 + fr;
            a[i] = *(const short8v*)&sA[ra * 128 + (k0 ^ ((ra & 7) << 3))];
            int rb = wn + i * 16 + fr;
            bb[i] = *(const short8v*)&sB[rb * 128 + (k0 ^ ((rb & 7) << 3))];
        }
#pragma unroll
        for (int mi = 0; mi < 4; ++mi)
#pragma unroll
            for (int ni = 0; ni < 4; ++ni)
                acc[mi][ni] = __builtin_amdgcn_mfma_f32_16x16x32_bf16(a[mi], bb[ni], acc[mi][ni], 0, 0, 0);
    }

#pragma unroll
    for (int mi = 0; mi < 4; ++mi)
#pragma unroll
        for (int ni = 0; ni < 4; ++ni) {
            int gp = nTile + wn + ni * 16 + fr;
#pragma unroll
            for (int r = 0; r < 4; ++r) {
                int o = wp + mi * 16 + fq * 4 + r;
                yw[(size_t)o * NPIX + gp] = acc[mi][ni][r];
            }
        }
}

__global__ __launch_bounds__(256) void k_stats(const float* __restrict__ yw,
                                               float* __restrict__ meanvar) {
    int o = blockIdx.x, t = threadIdx.x;
    __shared__ float rs[256], rq[256];
    float s = 0.f, q = 0.f;
    const float* p = yw + (size_t)o * NPIX;
    for (int i = t; i < NPIX; i += 256) {
        float v = p[i];
        s += v;
        q += v * v;
    }
    rs[t] = s; rq[t] = q;
    __syncthreads();
    for (int off = 128; off > 0; off >>= 1) {
        if (t < off) { rs[t] += rs[t + off]; rq[t] += rq[t + off]; }
        __syncthreads();
    }
    if (t == 0) {
        float n = (float)NPIX;
        float mean = rs[0] / n;
        float var  = rq[0] / n - mean * mean;
        meanvar[o] = mean;
        meanvar[CA + o] = var;
    }
}

__global__ __launch_bounds__(256) void k_final(const float* __restrict__ yw,
                                               const float* __restrict__ meanvar,
                                               const float* __restrict__ gamma,
                                               const float* __restrict__ beta,
                                               const float* __restrict__ alpha,
                                               float* __restrict__ out0) {
    size_t i = ((size_t)blockIdx.x * 256 + threadIdx.x) * 4;
    int c = (int)((i >> 14) & 127);
    int b = (int)(i >> 21);
    int pix = (int)(i & 16383);
    float4 v = *(const float4*)(yw + (size_t)c * NPIX + b * 16384 + pix);
    float4 a = *(const float4*)(alpha + i);
    float mean = meanvar[c];
    float var  = meanvar[CA + c];
    float sc   = rsqrtf(var + 1e-5f) * gamma[c];
    float bt   = beta[c];
    float4 r;
    r.x = (v.x - mean) * sc + bt + a.x;
    r.y = (v.y - mean) * sc + bt + a.y;
    r.z = (v.z - mean) * sc + bt + a.z;
    r.w = (v.w - mean) * sc + bt + a.w;
    *(float4*)(out0 + i) = r;
}

extern "C" void kernel_launch(void* const* d_in, const int* in_sizes, int n_in,
                              void* d_out, int out_size, void* d_ws, size_t ws_size,
                              hipStream_t stream) {
    (void)in_sizes; (void)n_in; (void)out_size;
    const float* f     = (const float*)d_in[0];
    const float* alpha = (const float*)d_in[1];
    const float* unk   = (const float*)d_in[2];
    const float* gw    = (const float*)d_in[3];
    const float* gb    = (const float*)d_in[4];
    const float* ww    = (const float*)d_in[5];
    const float* gamma = (const float*)d_in[6];
    const float* beta  = (const float*)d_in[7];

    float* out0 = (float*)d_out;
    float* out1 = out0 + (size_t)B * CA * H * W_;
    float* out2 = out1 + (size_t)B * 2 * HS * WS;

    // ---- persistent region ----
    float* wsf = (float*)d_ws;
    size_t off = 0;
    float* fds     = wsf + off; off += (size_t)B * CM * HS * WS;
    float* ssq     = wsf + off; off += (size_t)B * HS * WS;
    float* gbuf    = wsf + off; off += (size_t)B * L;
    float* dgbuf   = wsf + off; off += (size_t)B * L;
    float* suk     = wsf + off; off += 64;
    float* ytF     = wsf + off; off += (size_t)NPIX * 128 / 2;
    float* wwbfF   = wsf + off; off += 8192;
    float* meanvar = wsf + off; off += 256;
    float* rowinv  = wsf + off; off += (size_t)B * L;
    float* base    = wsf + off;

    const size_t PRE_F = off;
    // nb even only: gemm2 grid 16*8*nb must be a multiple of 256 CUs (R15 lesson).
    int nb = (ws_size >= (PRE_F + 4 * SLOT_F) * sizeof(float)) ? 4 : 2;

    float* yw   = base;
    u16*   yt   = (u16*)ytF;
    u16*   wwbf = (u16*)wwbfF;

    k_cvtww<<<64, 256, 0, stream>>>(ww, wwbf);
    k_conv_ds<<<dim3(64, 4), 256, 0, stream>>>(f, gw, gb, fds, ssq);
    k_scale<<<4, 256, 0, stream>>>(unk, suk, out2);
    k_gate<<<dim3(64, 4), 64, 0, stream>>>(unk, ssq, suk, gbuf, dgbuf);

    for (int b0 = 0; b0 < B; b0 += nb) {
        k_buildW<<<dim3(64, 32, nb), dim3(64, 4), 0, stream>>>(fds, base, b0);
        k_gemm1<<<dim3(528, 1, nb), 256, 0, stream>>>(base, gbuf, dgbuf, b0);
        k_softmax<<<dim3(4096, nb), 256, 0, stream>>>(base, fds, gbuf, dgbuf, rowinv, out1, b0);
        k_buildA<<<dim3(4, 2048, nb), 256, 0, stream>>>(alpha, base, b0);
        k_gemm2<<<dim3(16, 8, nb), 512, 0, stream>>>(base);
        k_gather<<<dim3(64, 128, nb), 256, 0, stream>>>(base, rowinv, yt, b0);
    }

    k_ywgemm<<<512, 256, 0, stream>>>(wwbf, yt, yw);
    k_stats<<<128, 256, 0, stream>>>(yw, meanvar);
    k_final<<<8192, 256, 0, stream>>>(yw, meanvar, gamma, beta, alpha, out0);
}